// Round 1
// baseline (240.852 us; speedup 1.0000x reference)
//
#include <hip/hip_runtime.h>
#include <hip/hip_bf16.h>
#include <cstdint>

#define DEVI __device__ __forceinline__

typedef __bf16 bf16x8 __attribute__((ext_vector_type(8)));
typedef float  f32x4  __attribute__((ext_vector_type(4)));

constexpr int Hdim = 1024;
constexpr int Vdim = 32000;
constexpr int Ldim = 512;
constexpr int Bdim = 256;

DEVI unsigned short f2bf(float f) {
  __bf16 h = (__bf16)f;                       // RNE
  return __builtin_bit_cast(unsigned short, h);
}

// ---------------------------------------------------------------------------
// Generic BT-GEMM: C[M x N] = A[M x K] @ W[N x K]^T  (+bias, optional ReLU)
//   A: fp32 (ABF16=false) or bf16 (ABF16=true), row-major, ld = K
//   W: fp32 row-major [N x K]  (converted to bf16 during staging)
//   C: fp32, element (row, col) written to C[row*ldc + col_off + col]
// Block: 256 threads = 4 waves; tile = (4*WM) x 64; K-step = 32.
// mfma_f32_16x16x32_bf16; A/B frag: lane holds X[lane%16][8*(lane>>4)+e],
// C/D frag: col = lane&15, row = (lane>>4)*4 + reg  (learn_hip m89-verified).
// ---------------------------------------------------------------------------
template<int WM, bool ABF16>
__global__ __launch_bounds__(256, 2)
void gemm_bt(const void* __restrict__ Av, const float* __restrict__ Wt,
             const float* __restrict__ bias, float* __restrict__ C,
             int K, int ldc, int col_off, int act)
{
  constexpr int MT    = 4 * WM;   // 128 or 256
  constexpr int PITCH = 40;       // bf16 elems per LDS row (32 + 8 pad)
  constexpr int ITA   = MT / 32;  // staging iterations for A tile
  constexpr int MR    = WM / 16;  // A frags per wave

  __shared__ unsigned short lA[MT * PITCH];
  __shared__ unsigned short lW[64 * PITCH];

  const int t  = threadIdx.x;
  const int m0 = blockIdx.y * MT;
  const int n0 = blockIdx.x * 64;
  const int NK = K >> 5;

  // staging: 8 threads per row, 4 elems (k) each -> 32 k per row
  const int tr = t >> 3;          // 0..31
  const int tc = (t & 7) * 4;     // k offset

  const float*          Af = ABF16 ? nullptr : ((const float*)Av) + (size_t)m0 * K;
  const unsigned short* Ab = ABF16 ? ((const unsigned short*)Av) + (size_t)m0 * K : nullptr;
  const float*          Wb = Wt + (size_t)n0 * K;

  f32x4   ra[ITA];
  ushort4 rab[ITA];
  f32x4   rw[2];

  auto loadT = [&](int kt) {
    if constexpr (ABF16) {
      const unsigned short* ap = Ab + kt * 32 + tc;
#pragma unroll
      for (int i = 0; i < ITA; ++i)
        rab[i] = *reinterpret_cast<const ushort4*>(ap + (size_t)(tr + 32 * i) * K);
    } else {
      const float* ap = Af + kt * 32 + tc;
#pragma unroll
      for (int i = 0; i < ITA; ++i)
        ra[i] = *reinterpret_cast<const f32x4*>(ap + (size_t)(tr + 32 * i) * K);
    }
    const float* wp = Wb + kt * 32 + tc;
#pragma unroll
    for (int i = 0; i < 2; ++i)
      rw[i] = *reinterpret_cast<const f32x4*>(wp + (size_t)(tr + 32 * i) * K);
  };

  auto storeT = [&]() {
#pragma unroll
    for (int i = 0; i < ITA; ++i) {
      ushort4 u;
      if constexpr (ABF16) u = rab[i];
      else { u.x = f2bf(ra[i][0]); u.y = f2bf(ra[i][1]);
             u.z = f2bf(ra[i][2]); u.w = f2bf(ra[i][3]); }
      *reinterpret_cast<ushort4*>(&lA[(tr + 32 * i) * PITCH + tc]) = u;
    }
#pragma unroll
    for (int i = 0; i < 2; ++i) {
      ushort4 u;
      u.x = f2bf(rw[i][0]); u.y = f2bf(rw[i][1]);
      u.z = f2bf(rw[i][2]); u.w = f2bf(rw[i][3]);
      *reinterpret_cast<ushort4*>(&lW[(tr + 32 * i) * PITCH + tc]) = u;
    }
  };

  const int lane = t & 63;
  const int wv   = t >> 6;            // wave 0..3 -> rows wv*WM .. +WM
  const int r16  = lane & 15;
  const int k8   = (lane >> 4) * 8;

  f32x4 acc[MR][4];
#pragma unroll
  for (int m = 0; m < MR; ++m)
#pragma unroll
    for (int n = 0; n < 4; ++n)
#pragma unroll
      for (int r = 0; r < 4; ++r) acc[m][n][r] = 0.f;

  loadT(0);
  storeT();
  __syncthreads();

  for (int kt = 0; kt < NK; ++kt) {
    if (kt + 1 < NK) loadT(kt + 1);   // prefetch next tile into regs

    bf16x8 af[MR], bfr[4];
#pragma unroll
    for (int m = 0; m < MR; ++m)
      af[m] = *reinterpret_cast<const bf16x8*>(&lA[(wv * WM + m * 16 + r16) * PITCH + k8]);
#pragma unroll
    for (int n = 0; n < 4; ++n)
      bfr[n] = *reinterpret_cast<const bf16x8*>(&lW[(n * 16 + r16) * PITCH + k8]);

#pragma unroll
    for (int m = 0; m < MR; ++m)
#pragma unroll
      for (int n = 0; n < 4; ++n)
        acc[m][n] = __builtin_amdgcn_mfma_f32_16x16x32_bf16(af[m], bfr[n], acc[m][n], 0, 0, 0);

    __syncthreads();
    if (kt + 1 < NK) storeT();
    __syncthreads();
  }

  // epilogue
#pragma unroll
  for (int n = 0; n < 4; ++n) {
    const int col = n0 + n * 16 + r16;
    const float bv = bias ? bias[col] : 0.f;
#pragma unroll
    for (int m = 0; m < MR; ++m) {
      const int rbase = m0 + wv * WM + m * 16 + (lane >> 4) * 4;
#pragma unroll
      for (int r = 0; r < 4; ++r) {
        float v = acc[m][n][r] + bv;
        if (act) v = fmaxf(v, 0.f);
        C[(size_t)(rbase + r) * ldc + col_off + col] = v;
      }
    }
  }
}

// ------------------- prep: X0 = [emb[id] | h], X1 left = emb[id] -------------
__global__ void prep_kernel(const int* __restrict__ ids, const float* __restrict__ hid,
                            const float* __restrict__ emb,
                            float* __restrict__ X0, float* __restrict__ X1)
{
  const int b = blockIdx.x, t = threadIdx.x;
  const int row = ids[b];
  f32x4 e = *reinterpret_cast<const f32x4*>(emb + (size_t)row * Hdim + t * 4);
  *reinterpret_cast<f32x4*>(X0 + (size_t)b * 2048 + t * 4) = e;
  *reinterpret_cast<f32x4*>(X1 + (size_t)b * 2048 + t * 4) = e;
  f32x4 h = *reinterpret_cast<const f32x4*>(hid + (size_t)b * Hdim + t * 4);
  *reinterpret_cast<f32x4*>(X0 + (size_t)b * 2048 + 1024 + t * 4) = h;
}

// ------------------- encoder transpose: encT[h][l] = enc[l][h] ---------------
__global__ void transpose_kernel(const float* __restrict__ enc, float* __restrict__ encT)
{
  __shared__ float tile[64][65];
  const int l0 = blockIdx.x * 64, h0 = blockIdx.y * 64;
  const int t = threadIdx.x;
  const int c = t & 63, rr = t >> 6;
#pragma unroll
  for (int p = 0; p < 16; ++p) {
    const int r = p * 4 + rr;
    tile[r][c] = enc[(size_t)(l0 + r) * Hdim + h0 + c];
  }
  __syncthreads();
#pragma unroll
  for (int p = 0; p < 16; ++p) {
    const int r = p * 4 + rr;
    encT[(size_t)(h0 + r) * Ldim + l0 + c] = tile[c][r];
  }
}

// ------------------- softmax over L=512 per row ------------------------------
__global__ void attn_softmax_kernel(const float* __restrict__ logits, float* __restrict__ wout)
{
  __shared__ float red[256];
  const int b = blockIdx.x, t = threadIdx.x;
  const float x0 = logits[b * Ldim + t];
  const float x1 = logits[b * Ldim + 256 + t];
  red[t] = fmaxf(x0, x1); __syncthreads();
  for (int o = 128; o > 0; o >>= 1) { if (t < o) red[t] = fmaxf(red[t], red[t + o]); __syncthreads(); }
  const float m = red[0]; __syncthreads();
  const float e0 = __expf(x0 - m), e1 = __expf(x1 - m);
  red[t] = e0 + e1; __syncthreads();
  for (int o = 128; o > 0; o >>= 1) { if (t < o) red[t] += red[t + o]; __syncthreads(); }
  const float inv = 1.f / red[0];
  wout[b * Ldim + t]       = e0 * inv;
  wout[b * Ldim + 256 + t] = e1 * inv;
}

// ------------------- GRU pointwise ------------------------------------------
DEVI float sigm(float x) { return 1.f / (1.f + __expf(-x)); }

__global__ void gru_kernel(const float* __restrict__ gi, const float* __restrict__ gh,
                           const float* __restrict__ hin,
                           float* __restrict__ hnew, unsigned short* __restrict__ hnbf)
{
  const int idx = blockIdx.x * 256 + threadIdx.x;       // < B*H
  const int b = idx >> 10, j = idx & 1023;
  const float* gib = gi + (size_t)b * 3072;
  const float* ghb = gh + (size_t)b * 3072;
  const float r = sigm(gib[j] + ghb[j]);
  const float z = sigm(gib[1024 + j] + ghb[1024 + j]);
  const float n = tanhf(gib[2048 + j] + r * ghb[2048 + j]);
  const float h = hin[idx];
  const float hn = (1.f - z) * n + z * h;
  hnew[idx] = hn;
  hnbf[idx] = f2bf(hn);
}

// ------------------- fused logsumexp + in-place log_softmax ------------------
__global__ void lsm_kernel(float* __restrict__ out)
{
  __shared__ float rm[256], rs[256];
  const int b = blockIdx.x, t = threadIdx.x;
  float* row = out + (size_t)b * Vdim;
  float m = -1e30f, s = 0.f;
  for (int v = t; v < Vdim; v += 256) {
    const float x = row[v];
    const float nm = fmaxf(m, x);
    s = s * __expf(m - nm) + __expf(x - nm);
    m = nm;
  }
  rm[t] = m; rs[t] = s; __syncthreads();
  for (int o = 128; o > 0; o >>= 1) {
    if (t < o) {
      const float m2 = rm[t + o], s2 = rs[t + o];
      const float nm = fmaxf(rm[t], m2);
      rs[t] = rs[t] * __expf(rm[t] - nm) + s2 * __expf(m2 - nm);
      rm[t] = nm;
    }
    __syncthreads();
  }
  const float lse = rm[0] + __logf(rs[0]);
  for (int v = t; v < Vdim; v += 256) row[v] -= lse;
}

// ---------------------------------------------------------------------------
extern "C" void kernel_launch(void* const* d_in, const int* in_sizes, int n_in,
                              void* d_out, int out_size, void* d_ws, size_t ws_size,
                              hipStream_t stream)
{
  (void)in_sizes; (void)n_in; (void)out_size; (void)ws_size;

  const int*   ids    = (const int*)  d_in[0];
  const float* hid    = (const float*)d_in[1];   // [1,B,H] -> [B,H]
  const float* enc    = (const float*)d_in[2];   // [L,H]
  const float* emb    = (const float*)d_in[3];   // [V,H]
  const float* attn_W = (const float*)d_in[4];   // [L,2H]
  const float* attn_b = (const float*)d_in[5];
  const float* comb_W = (const float*)d_in[6];   // [H,2H]
  const float* comb_b = (const float*)d_in[7];
  const float* W_ih   = (const float*)d_in[8];   // [3H,H]
  const float* W_hh   = (const float*)d_in[9];   // [3H,H]
  const float* b_ih   = (const float*)d_in[10];
  const float* b_hh   = (const float*)d_in[11];
  const float* out_W  = (const float*)d_in[12];  // [V,H]
  const float* out_b  = (const float*)d_in[13];

  float* out_logits = (float*)d_out;                       // [B,V]
  float* out_h      = out_logits + (size_t)Bdim * Vdim;    // [B,H]
  float* out_attw   = out_h + (size_t)Bdim * Hdim;         // [B,L]

  char* w = (char*)d_ws;
  float* X0   = (float*)w; w += (size_t)Bdim * 2048 * 4;       // [B, 2H] = [emb | h]
  float* X1   = (float*)w; w += (size_t)Bdim * 2048 * 4;       // [B, 2H] = [emb | attn_applied]
  float* encT = (float*)w; w += (size_t)Hdim * Ldim * 4;       // [H, L]
  float* alog = (float*)w; w += (size_t)Bdim * Ldim * 4;       // attn logits [B,L]
  float* xact = (float*)w; w += (size_t)Bdim * Hdim * 4;       // relu(comb) [B,H]
  float* gi   = (float*)w; w += (size_t)Bdim * 3 * Hdim * 4;   // [B,3H]
  float* gh   = (float*)w; w += (size_t)Bdim * 3 * Hdim * 4;   // [B,3H]
  unsigned short* hnbf = (unsigned short*)w; w += (size_t)Bdim * Hdim * 2; // h_new bf16

  prep_kernel<<<Bdim, 256, 0, stream>>>(ids, hid, emb, X0, X1);
  transpose_kernel<<<dim3(Ldim / 64, Hdim / 64), 256, 0, stream>>>(enc, encT);

  // attn logits [B,L] = X0 @ attn_W^T + attn_b
  gemm_bt<32, false><<<dim3(Ldim / 64, 2), 256, 0, stream>>>(X0, attn_W, attn_b, alog,
                                                             2048, Ldim, 0, 0);
  attn_softmax_kernel<<<Bdim, 256, 0, stream>>>(alog, out_attw);

  // attn_applied [B,H] = attn_w @ encT^T -> X1 right half
  gemm_bt<32, false><<<dim3(Hdim / 64, 2), 256, 0, stream>>>(out_attw, encT, nullptr, X1,
                                                             Ldim, 2048, 1024, 0);
  // x = relu(X1 @ comb_W^T + comb_b)
  gemm_bt<32, false><<<dim3(Hdim / 64, 2), 256, 0, stream>>>(X1, comb_W, comb_b, xact,
                                                             2048, Hdim, 0, 1);
  // gi = x @ W_ih^T + b_ih ; gh = h @ W_hh^T + b_hh
  gemm_bt<32, false><<<dim3(3 * Hdim / 64, 2), 256, 0, stream>>>(xact, W_ih, b_ih, gi,
                                                                 Hdim, 3 * Hdim, 0, 0);
  gemm_bt<32, false><<<dim3(3 * Hdim / 64, 2), 256, 0, stream>>>(hid, W_hh, b_hh, gh,
                                                                 Hdim, 3 * Hdim, 0, 0);
  gru_kernel<<<Bdim * Hdim / 256, 256, 0, stream>>>(gi, gh, hid, out_h, hnbf);

  // logits [B,V] = h_new @ out_W^T + out_b   (full-M tile so out_W read once)
  gemm_bt<64, true><<<dim3(Vdim / 64, 1), 256, 0, stream>>>(hnbf, out_W, out_b, out_logits,
                                                            Hdim, Vdim, 0, 0);
  lsm_kernel<<<Bdim, 256, 0, stream>>>(out_logits);
}

// Round 2
// 129.702 us; speedup vs baseline: 1.8570x; 1.8570x over previous
//
#include <hip/hip_runtime.h>
#include <hip/hip_bf16.h>
#include <cstdint>

#define DEVI __device__ __forceinline__

typedef __bf16 bf16x8 __attribute__((ext_vector_type(8)));
typedef float  f32x4  __attribute__((ext_vector_type(4)));

constexpr int Hdim = 1024;
constexpr int Vdim = 32000;
constexpr int Ldim = 512;
constexpr int Bdim = 256;

DEVI unsigned short f2bf(float f) {
  __bf16 h = (__bf16)f;                       // RNE
  return __builtin_bit_cast(unsigned short, h);
}

// ---------------------------------------------------------------------------
// Pipelined BT-GEMM: C[M x N(=64/blk)] = A[M x K] @ W[N x K]^T
//   - double-buffered LDS, one raw s_barrier per K-step (lgkm drain only, NO
//     vmcnt drain -> depth-2 global prefetch stays in flight across barriers)
//   - nsplit>1: K split across blockIdx.z, epilogue atomicAdd (C pre-init'd
//     with bias by prep kernel)
//   - DUAL: blockIdx.z in [0,2*nsplit): low half = problem 0, high = problem 1
//   - aact0: apply ReLU to A (problem 0) while staging fp32->bf16
//   - plse: per-block per-row online-softmax partials {max, sum} (big GEMM)
// MFMA 16x16x32_bf16; C/D: col=lane&15, row=(lane>>4)*4+reg (m89-verified).
// NK per block MUST be even and >= 2.
// ---------------------------------------------------------------------------
template<int WM, bool ABF16, bool DUAL>
__global__ __launch_bounds__(256, 2)
void gemm_bt(const void* __restrict__ Av0, const float* __restrict__ Wt0,
             const void* __restrict__ Av1, const float* __restrict__ Wt1,
             const float* __restrict__ bias,
             float* __restrict__ C0, float* __restrict__ C1,
             int K, int ldc, int col_off, int act, int aact0,
             int nsplit, float2* __restrict__ plse)
{
  constexpr int MT    = 4 * WM;   // 128 or 256
  constexpr int PITCH = 40;       // bf16 elems per LDS row (32 + 8 pad)
  constexpr int ITA   = MT / 32;
  constexpr int MR    = WM / 16;

  __shared__ unsigned short lA[2 * MT * PITCH];
  __shared__ unsigned short lW[2 * 64 * PITCH];

  const int t  = threadIdx.x;
  const int m0 = blockIdx.y * MT;
  const int n0 = blockIdx.x * 64;

  int kz = blockIdx.z, half = 0;
  if (DUAL) { half = (kz >= nsplit) ? 1 : 0; kz -= half * nsplit; }
  const int NK = K / (32 * nsplit);
  const int kb = kz * NK;                       // base k-tile index

  const void*  Av = (DUAL && half) ? Av1 : Av0;
  const float* Wt = (DUAL && half) ? Wt1 : Wt0;
  float*       C  = (DUAL && half) ? C1  : C0;
  const int  aact = (DUAL && half) ? 0 : aact0;

  const int tr = t >> 3;          // 0..31 (row within 32-row staging group)
  const int tc = (t & 7) * 4;     // k offset

  const float*          Af = ABF16 ? nullptr : ((const float*)Av) + (size_t)m0 * K;
  const unsigned short* Ab = ABF16 ? ((const unsigned short*)Av) + (size_t)m0 * K : nullptr;
  const float*          Wb = Wt + (size_t)n0 * K;

  const int lane = t & 63;
  const int wv   = t >> 6;
  const int r16  = lane & 15;
  const int k8   = (lane >> 4) * 8;

  f32x4 acc[MR][4];
#pragma unroll
  for (int m = 0; m < MR; ++m)
#pragma unroll
    for (int n = 0; n < 4; ++n)
#pragma unroll
      for (int r = 0; r < 4; ++r) acc[m][n][r] = 0.f;

  struct RS { f32x4 ra[ITA]; ushort4 rab[ITA]; f32x4 rw[2]; };

  auto loadT = [&](RS& rg, int kt) {
    const int ko = (kb + kt) * 32 + tc;
    if constexpr (ABF16) {
      const unsigned short* ap = Ab + ko;
#pragma unroll
      for (int i = 0; i < ITA; ++i)
        rg.rab[i] = *reinterpret_cast<const ushort4*>(ap + (size_t)(tr + 32 * i) * K);
    } else {
      const float* ap = Af + ko;
#pragma unroll
      for (int i = 0; i < ITA; ++i)
        rg.ra[i] = *reinterpret_cast<const f32x4*>(ap + (size_t)(tr + 32 * i) * K);
    }
    const float* wp = Wb + ko;
#pragma unroll
    for (int i = 0; i < 2; ++i)
      rg.rw[i] = *reinterpret_cast<const f32x4*>(wp + (size_t)(tr + 32 * i) * K);
  };

  auto storeT = [&](RS& rg, int bo) {
    unsigned short* sA = &lA[bo * MT * PITCH];
    unsigned short* sW = &lW[bo * 64 * PITCH];
#pragma unroll
    for (int i = 0; i < ITA; ++i) {
      ushort4 u;
      if constexpr (ABF16) u = rg.rab[i];
      else {
        f32x4 v = rg.ra[i];
        if (aact) { v[0]=fmaxf(v[0],0.f); v[1]=fmaxf(v[1],0.f);
                    v[2]=fmaxf(v[2],0.f); v[3]=fmaxf(v[3],0.f); }
        u.x = f2bf(v[0]); u.y = f2bf(v[1]); u.z = f2bf(v[2]); u.w = f2bf(v[3]);
      }
      *reinterpret_cast<ushort4*>(&sA[(tr + 32 * i) * PITCH + tc]) = u;
    }
#pragma unroll
    for (int i = 0; i < 2; ++i) {
      f32x4 v = rg.rw[i]; ushort4 u;
      u.x = f2bf(v[0]); u.y = f2bf(v[1]); u.z = f2bf(v[2]); u.w = f2bf(v[3]);
      *reinterpret_cast<ushort4*>(&sW[(tr + 32 * i) * PITCH + tc]) = u;
    }
  };

  auto comp = [&](int bo) {
    const unsigned short* sA = &lA[bo * MT * PITCH];
    const unsigned short* sW = &lW[bo * 64 * PITCH];
    bf16x8 af[MR], bfr[4];
#pragma unroll
    for (int m = 0; m < MR; ++m)
      af[m] = *reinterpret_cast<const bf16x8*>(&sA[(wv * WM + m * 16 + r16) * PITCH + k8]);
#pragma unroll
    for (int n = 0; n < 4; ++n)
      bfr[n] = *reinterpret_cast<const bf16x8*>(&sW[(n * 16 + r16) * PITCH + k8]);
#pragma unroll
    for (int m = 0; m < MR; ++m)
#pragma unroll
      for (int n = 0; n < 4; ++n)
        acc[m][n] = __builtin_amdgcn_mfma_f32_16x16x32_bf16(af[m], bfr[n], acc[m][n], 0, 0, 0);
  };

#define GB_BARRIER() do { \
    asm volatile("s_waitcnt lgkmcnt(0)" ::: "memory"); \
    __builtin_amdgcn_sched_barrier(0); \
    __builtin_amdgcn_s_barrier(); \
  } while (0)

  RS ra_, rb_;
  loadT(ra_, 0);
  loadT(rb_, 1);
  storeT(ra_, 0);
  GB_BARRIER();

  for (int kt = 0; kt < NK; kt += 2) {
    // even step: read buf0, fill buf1 with tile kt+1
    if (kt + 2 < NK) loadT(ra_, kt + 2);
    comp(0);
    storeT(rb_, 1);
    GB_BARRIER();
    // odd step: read buf1, fill buf0 with tile kt+2
    if (kt + 3 < NK) loadT(rb_, kt + 3);
    comp(1);
    if (kt + 2 < NK) {
      storeT(ra_, 0);
      GB_BARRIER();
    }
  }
#undef GB_BARRIER

  // ---------------- epilogue ----------------
#pragma unroll
  for (int n = 0; n < 4; ++n) {
    const int col = n0 + n * 16 + r16;
    const float bv = (bias && nsplit == 1) ? bias[col] : 0.f;
#pragma unroll
    for (int m = 0; m < MR; ++m) {
      const int rbase = m0 + wv * WM + m * 16 + (lane >> 4) * 4;
#pragma unroll
      for (int r = 0; r < 4; ++r) {
        float v = acc[m][n][r] + bv;
        if (act) v = fmaxf(v, 0.f);
        if (nsplit > 1) {
          atomicAdd(&C[(size_t)(rbase + r) * ldc + col_off + col], v);
        } else {
          C[(size_t)(rbase + r) * ldc + col_off + col] = v;
          acc[m][n][r] = v;            // keep biased value for plse
        }
      }
    }
  }

  if (plse) {   // per-row online-softmax partials over this block's 64 cols
#pragma unroll
    for (int m = 0; m < MR; ++m) {
#pragma unroll
      for (int r = 0; r < 4; ++r) {
        float mx = fmaxf(fmaxf(acc[m][0][r], acc[m][1][r]),
                         fmaxf(acc[m][2][r], acc[m][3][r]));
#pragma unroll
        for (int o = 1; o < 16; o <<= 1) mx = fmaxf(mx, __shfl_xor(mx, o, 16));
        float s = 0.f;
#pragma unroll
        for (int n = 0; n < 4; ++n) s += __expf(acc[m][n][r] - mx);
#pragma unroll
        for (int o = 1; o < 16; o <<= 1) s += __shfl_xor(s, o, 16);
        if (r16 == 0) {
          const int row = m0 + wv * WM + m * 16 + (lane >> 4) * 4 + r;
          plse[(size_t)row * gridDim.x + blockIdx.x] = make_float2(mx, s);
        }
      }
    }
  }
}

// ---- prep: X0=[emb|h], X1=[emb|0]; bias-init alog/xact/gi/gh ---------------
__global__ void prep_kernel(const int* __restrict__ ids, const float* __restrict__ hid,
                            const float* __restrict__ emb,
                            const float* __restrict__ attn_b, const float* __restrict__ comb_b,
                            const float* __restrict__ b_ih, const float* __restrict__ b_hh,
                            float* __restrict__ X0, float* __restrict__ X1,
                            float* __restrict__ alog, float* __restrict__ xact,
                            float* __restrict__ gi, float* __restrict__ gh)
{
  const int b = blockIdx.x, t = threadIdx.x;
  const int row = ids[b];
  f32x4 e = *reinterpret_cast<const f32x4*>(emb + (size_t)row * Hdim + t * 4);
  *reinterpret_cast<f32x4*>(X0 + (size_t)b * 2048 + t * 4) = e;
  *reinterpret_cast<f32x4*>(X1 + (size_t)b * 2048 + t * 4) = e;
  f32x4 h = *reinterpret_cast<const f32x4*>(hid + (size_t)b * Hdim + t * 4);
  *reinterpret_cast<f32x4*>(X0 + (size_t)b * 2048 + 1024 + t * 4) = h;
  f32x4 z4 = {0.f, 0.f, 0.f, 0.f};
  *reinterpret_cast<f32x4*>(X1 + (size_t)b * 2048 + 1024 + t * 4) = z4;
  if (t < 128)
    *reinterpret_cast<f32x4*>(alog + (size_t)b * Ldim + t * 4) =
        *reinterpret_cast<const f32x4*>(attn_b + t * 4);
  *reinterpret_cast<f32x4*>(xact + (size_t)b * Hdim + t * 4) =
      *reinterpret_cast<const f32x4*>(comb_b + t * 4);
#pragma unroll
  for (int i = 0; i < 3; ++i) {
    *reinterpret_cast<f32x4*>(gi + (size_t)b * 3072 + i * 1024 + t * 4) =
        *reinterpret_cast<const f32x4*>(b_ih + i * 1024 + t * 4);
    *reinterpret_cast<f32x4*>(gh + (size_t)b * 3072 + i * 1024 + t * 4) =
        *reinterpret_cast<const f32x4*>(b_hh + i * 1024 + t * 4);
  }
}

// ---- encoder transpose: encT[h][l] = enc[l][h] -----------------------------
__global__ void transpose_kernel(const float* __restrict__ enc, float* __restrict__ encT)
{
  __shared__ float tile[64][65];
  const int l0 = blockIdx.x * 64, h0 = blockIdx.y * 64;
  const int t = threadIdx.x;
  const int c = t & 63, rr = t >> 6;
#pragma unroll
  for (int p = 0; p < 16; ++p) {
    const int r = p * 4 + rr;
    tile[r][c] = enc[(size_t)(l0 + r) * Hdim + h0 + c];
  }
  __syncthreads();
#pragma unroll
  for (int p = 0; p < 16; ++p) {
    const int r = p * 4 + rr;
    encT[(size_t)(h0 + r) * Ldim + l0 + c] = tile[c][r];
  }
}

// ---- softmax over L=512 per row --------------------------------------------
__global__ void attn_softmax_kernel(const float* __restrict__ logits, float* __restrict__ wout)
{
  __shared__ float red[256];
  const int b = blockIdx.x, t = threadIdx.x;
  const float x0 = logits[b * Ldim + t];
  const float x1 = logits[b * Ldim + 256 + t];
  red[t] = fmaxf(x0, x1); __syncthreads();
  for (int o = 128; o > 0; o >>= 1) { if (t < o) red[t] = fmaxf(red[t], red[t + o]); __syncthreads(); }
  const float m = red[0]; __syncthreads();
  const float e0 = __expf(x0 - m), e1 = __expf(x1 - m);
  red[t] = e0 + e1; __syncthreads();
  for (int o = 128; o > 0; o >>= 1) { if (t < o) red[t] += red[t + o]; __syncthreads(); }
  const float inv = 1.f / red[0];
  wout[b * Ldim + t]       = e0 * inv;
  wout[b * Ldim + 256 + t] = e1 * inv;
}

// ---- GRU pointwise ---------------------------------------------------------
DEVI float sigm(float x) { return 1.f / (1.f + __expf(-x)); }

__global__ void gru_kernel(const float* __restrict__ gi, const float* __restrict__ gh,
                           const float* __restrict__ hin,
                           float* __restrict__ hnew, unsigned short* __restrict__ hnbf)
{
  const int idx = blockIdx.x * 256 + threadIdx.x;       // < B*H
  const int b = idx >> 10, j = idx & 1023;
  const float* gib = gi + (size_t)b * 3072;
  const float* ghb = gh + (size_t)b * 3072;
  const float r = sigm(gib[j] + ghb[j]);
  const float z = sigm(gib[1024 + j] + ghb[1024 + j]);
  const float n = tanhf(gib[2048 + j] + r * ghb[2048 + j]);
  const float h = hin[idx];
  const float hn = (1.f - z) * n + z * h;
  hnew[idx] = hn;
  hnbf[idx] = f2bf(hn);
}

// ---- final: reduce per-block LSE partials, subtract in place ---------------
__global__ void lsm_final(const float2* __restrict__ part, int npart, float* __restrict__ out)
{
  __shared__ float rm[256], rs[256];
  const int b = blockIdx.x, t = threadIdx.x;
  float m = -1e30f, s = 0.f;
  for (int j = t; j < npart; j += 256) {
    const float2 p = part[(size_t)b * npart + j];
    const float nm = fmaxf(m, p.x);
    s = s * __expf(m - nm) + p.y * __expf(p.x - nm);
    m = nm;
  }
  rm[t] = m; rs[t] = s; __syncthreads();
  for (int o = 128; o > 0; o >>= 1) {
    if (t < o) {
      const float m2 = rm[t + o], s2 = rs[t + o];
      const float nm = fmaxf(rm[t], m2);
      rs[t] = rs[t] * __expf(rm[t] - nm) + s2 * __expf(m2 - nm);
      rm[t] = nm;
    }
    __syncthreads();
  }
  const float lse = rm[0] + __logf(rs[0]);
  f32x4* row4 = reinterpret_cast<f32x4*>(out + (size_t)b * Vdim);
  for (int i = t; i < Vdim / 4; i += 256) {
    f32x4 x = row4[i];
    x[0] -= lse; x[1] -= lse; x[2] -= lse; x[3] -= lse;
    row4[i] = x;
  }
}

// ---------------------------------------------------------------------------
extern "C" void kernel_launch(void* const* d_in, const int* in_sizes, int n_in,
                              void* d_out, int out_size, void* d_ws, size_t ws_size,
                              hipStream_t stream)
{
  (void)in_sizes; (void)n_in; (void)out_size; (void)ws_size;

  const int*   ids    = (const int*)  d_in[0];
  const float* hid    = (const float*)d_in[1];
  const float* enc    = (const float*)d_in[2];
  const float* emb    = (const float*)d_in[3];
  const float* attn_W = (const float*)d_in[4];
  const float* attn_b = (const float*)d_in[5];
  const float* comb_W = (const float*)d_in[6];
  const float* comb_b = (const float*)d_in[7];
  const float* W_ih   = (const float*)d_in[8];
  const float* W_hh   = (const float*)d_in[9];
  const float* b_ih   = (const float*)d_in[10];
  const float* b_hh   = (const float*)d_in[11];
  const float* out_W  = (const float*)d_in[12];
  const float* out_b  = (const float*)d_in[13];

  float* out_logits = (float*)d_out;                       // [B,V]
  float* out_h      = out_logits + (size_t)Bdim * Vdim;    // [B,H]
  float* out_attw   = out_h + (size_t)Bdim * Hdim;         // [B,L]

  char* w = (char*)d_ws;
  float* X0   = (float*)w; w += (size_t)Bdim * 2048 * 4;
  float* X1   = (float*)w; w += (size_t)Bdim * 2048 * 4;
  float* encT = (float*)w; w += (size_t)Hdim * Ldim * 4;
  float* alog = (float*)w; w += (size_t)Bdim * Ldim * 4;
  float* xact = (float*)w; w += (size_t)Bdim * Hdim * 4;
  float* gi   = (float*)w; w += (size_t)Bdim * 3 * Hdim * 4;
  float* gh   = (float*)w; w += (size_t)Bdim * 3 * Hdim * 4;
  unsigned short* hnbf = (unsigned short*)w; w += (size_t)Bdim * Hdim * 2;
  float2* plse = (float2*)w; w += (size_t)Bdim * (Vdim / 64) * 8;

  prep_kernel<<<Bdim, 256, 0, stream>>>(ids, hid, emb, attn_b, comb_b, b_ih, b_hh,
                                        X0, X1, alog, xact, gi, gh);
  transpose_kernel<<<dim3(Ldim / 64, Hdim / 64), 256, 0, stream>>>(enc, encT);

  // attn logits [B,L] += X0 @ attn_W^T   (split-K=8, bias pre-init)
  gemm_bt<32, false, false><<<dim3(Ldim / 64, 2, 8), 256, 0, stream>>>(
      X0, attn_W, nullptr, nullptr, nullptr, alog, nullptr,
      2048, Ldim, 0, 0, 0, 8, nullptr);
  attn_softmax_kernel<<<Bdim, 256, 0, stream>>>(alog, out_attw);

  // attn_applied [B,H] += attn_w @ encT^T -> X1 right half (split-K=4)
  gemm_bt<32, false, false><<<dim3(Hdim / 64, 2, 4), 256, 0, stream>>>(
      out_attw, encT, nullptr, nullptr, nullptr, X1, nullptr,
      512, 2048, 1024, 0, 0, 4, nullptr);

  // xact [B,H] += X1 @ comb_W^T  (split-K=8; ReLU deferred to gi's A-staging)
  gemm_bt<32, false, false><<<dim3(Hdim / 64, 2, 8), 256, 0, stream>>>(
      X1, comb_W, nullptr, nullptr, nullptr, xact, nullptr,
      2048, Hdim, 0, 0, 0, 8, nullptr);

  // gi += relu(xact) @ W_ih^T ; gh += h @ W_hh^T  (dual, split-K=4)
  gemm_bt<32, false, true><<<dim3(3 * Hdim / 64, 2, 8), 256, 0, stream>>>(
      xact, W_ih, hid, W_hh, nullptr, gi, gh,
      1024, 3 * Hdim, 0, 0, 1, 4, nullptr);

  gru_kernel<<<Bdim * Hdim / 256, 256, 0, stream>>>(gi, gh, hid, out_h, hnbf);

  // logits [B,V] = h_new @ out_W^T + out_b  (full-M tile, W read once, +LSE partials)
  gemm_bt<64, true, false><<<dim3(Vdim / 64, 1, 1), 256, 0, stream>>>(
      hnbf, out_W, nullptr, nullptr, out_b, out_logits, nullptr,
      1024, Vdim, 0, 0, 0, 1, plse);

  lsm_final<<<Bdim, 256, 0, stream>>>(plse, Vdim / 64, out_logits);
}